// Round 8
// baseline (108.817 us; speedup 1.0000x reference)
//
#include <hip/hip_runtime.h>

// ChamferLoss: prediction [B,N,3] f32, target [B,M,3] f32 -> scalar f32.
// v8: SMEM-fed main loop. R5-R7 calibration: duration == VALU-issue + LDS
// time, fully SERIALIZED (LDS b128 broadcast writeback contends with VALU
// VGPR ports; extra waves don't hide it). Fix: Y data arrives via
// s_load_dwordx16 into SGPRs (scalar pipe, no VGPR writeback). VOP3P takes
// 1 SGPR operand per instr: t=pk_fma(qz_v,z_v,w_s); t=pk_fma(qy_v,y_s,t);
// t=pk_fma(qx_v,x_s,t). Only z needs VGPR movs (4/group, amortized 8 rows).

#define BLOCK 256
#define RPT   8      // rows per thread
#define MC    256    // Y points per chunk
#define NPTS  8192   // N == M
#define NCH   (NPTS / MC)   // 32 chunks
#define NB    4      // batch
#define NGRP  (NPTS / 4)    // 4-point groups per (dir,b)
#define GPC   (MC / 4)      // 64 groups per chunk

typedef float v2f  __attribute__((ext_vector_type(2)));
typedef float v4f  __attribute__((ext_vector_type(4)));
typedef int   v16i __attribute__((ext_vector_type(16)));

__device__ __forceinline__ float min3f(float a, float b, float c) {
    float d;
    asm("v_min3_f32 %0, %1, %2, %3" : "=v"(d) : "v"(a), "v"(b), "v"(c));
    return d;
}
// d = a*b + c, c in SGPRs (1 scalar operand)
__device__ __forceinline__ v2f pk_fma_vvs(v2f a, v2f b, v2f c) {
    v2f d;
    asm("v_pk_fma_f32 %0, %1, %2, %3" : "=v"(d) : "v"(a), "v"(b), "s"(c));
    return d;
}
// d = a*b + c, b in SGPRs (1 scalar operand)
__device__ __forceinline__ v2f pk_fma_vsv(v2f a, v2f b, v2f c) {
    v2f d;
    asm("v_pk_fma_f32 %0, %1, %2, %3" : "=v"(d) : "v"(a), "s"(b), "v"(c));
    return d;
}

// Pack Y per 4-point group: [x0,x1, y0,y1, w0,w1, z0,z1 | x2,x3, y2,y3, w2,w3, z2,z3]
// dir0 packs targ (Y for pred->targ), dir1 packs pred.
__global__ __launch_bounds__(256) void pack_kernel(
    const float* __restrict__ pred, const float* __restrict__ targ,
    float* __restrict__ pk, double* __restrict__ acc,
    unsigned int* __restrict__ counter) {
    const int t = blockIdx.x * 256 + threadIdx.x;   // 0 .. 2*NB*NGRP-1
    if (t == 0) { *acc = 0.0; *counter = 0u; }      // stream-ordered init
    const int dir = t / (NB * NGRP);
    const int rem = t % (NB * NGRP);
    const int b = rem / NGRP, g = rem % NGRP;
    const float* Y = dir ? pred : targ;
    const float* yp = Y + ((size_t)b * NPTS + (size_t)g * 4) * 3;
    float out[16];
#pragma unroll
    for (int i = 0; i < 4; ++i) {
        float x = yp[3 * i], y = yp[3 * i + 1], z = yp[3 * i + 2];
        float w = fmaf(x, x, fmaf(y, y, z * z));
        int base = (i >> 1) * 8, sub = i & 1;
        out[base + 0 + sub] = x;
        out[base + 2 + sub] = y;
        out[base + 4 + sub] = w;
        out[base + 6 + sub] = z;
    }
    v4f* dst = (v4f*)(pk + (size_t)t * 16);
    const v4f* o = (const v4f*)out;
    dst[0] = o[0]; dst[1] = o[1]; dst[2] = o[2]; dst[3] = o[3];
}

__global__ __launch_bounds__(BLOCK) void chamfer_min_smem(
    const float* __restrict__ pred, const float* __restrict__ targ,
    const float* __restrict__ pk,
    float* __restrict__ pA,          // [B, NCH, N] partials, dir pred->targ
    float* __restrict__ pB) {        // [B, NCH, M] partials, dir targ->pred
    const int z = blockIdx.z;        // 0..2B-1: dir = z>>2, b = z&3
    const int dir = z >> 2, b = z & (NB - 1);
    const float* X = dir ? targ : pred;
    float* partial = dir ? pB : pA;
    const int mc = blockIdx.y;

    const int row0 = blockIdx.x * (BLOCK * RPT);
    v2f qx[RPT], qy[RPT], qz[RPT];
    float x2[RPT], best[RPT];
#pragma unroll
    for (int r = 0; r < RPT; ++r) {
        int row = row0 + r * BLOCK + threadIdx.x;
        const float* xp = X + ((size_t)b * NPTS + row) * 3;
        float px = xp[0], py = xp[1], pz = xp[2];
        qx[r] = (v2f){-2.0f * px, -2.0f * px};
        qy[r] = (v2f){-2.0f * py, -2.0f * py};
        qz[r] = (v2f){-2.0f * pz, -2.0f * pz};
        x2[r] = fmaf(px, px, fmaf(py, py, pz * pz));
        best[r] = 3.0e38f;
    }

#define AS2(S, i, j) (v2f){__int_as_float(S[i]), __int_as_float(S[j])}
#define COMPUTE(S) do {                                                   \
        v2f x01 = AS2(S, 0, 1),  y01 = AS2(S, 2, 3);                      \
        v2f w01 = AS2(S, 4, 5),  z01 = AS2(S, 6, 7);                      \
        v2f x23 = AS2(S, 8, 9),  y23 = AS2(S, 10, 11);                    \
        v2f w23 = AS2(S, 12, 13), z23 = AS2(S, 14, 15);                   \
        _Pragma("unroll")                                                 \
        for (int r = 0; r < RPT; ++r) {                                   \
            v2f t0 = pk_fma_vvs(qz[r], z01, w01);                         \
            t0 = pk_fma_vsv(qy[r], y01, t0);                              \
            t0 = pk_fma_vsv(qx[r], x01, t0);                              \
            v2f t1 = pk_fma_vvs(qz[r], z23, w23);                         \
            t1 = pk_fma_vsv(qy[r], y23, t1);                              \
            t1 = pk_fma_vsv(qx[r], x23, t1);                              \
            best[r] = min3f(best[r], t0.x, t0.y);                         \
            best[r] = min3f(best[r], t1.x, t1.y);                         \
        }                                                                 \
    } while (0)

    // SMEM stream over this chunk's 64 groups, prefetch depth 1.
    const float* base = pk + (((size_t)dir * NB + b) * NGRP + (size_t)mc * GPC) * 16;
    v16i cur, nxt;
    asm volatile("s_load_dwordx16 %0, %1, 0x0" : "=s"(cur) : "s"(base));
    asm volatile("s_waitcnt lgkmcnt(0)" ::: "memory");
    __builtin_amdgcn_sched_barrier(0);
    for (int j = 0; j < GPC - 1; ++j) {
        asm volatile("s_load_dwordx16 %0, %1, 0x40" : "=s"(nxt) : "s"(base));
        COMPUTE(cur);
        asm volatile("s_waitcnt lgkmcnt(0)" ::: "memory");   // nxt ready
        __builtin_amdgcn_sched_barrier(0);                   // rule #18 fence
        cur = nxt;
        base += 16;
    }
    COMPUTE(cur);

    // Coalesced per-chunk partial write (clamp + ||x||^2 folded in).
#pragma unroll
    for (int r = 0; r < RPT; ++r) {
        int row = row0 + r * BLOCK + threadIdx.x;
        partial[((size_t)b * NCH + mc) * NPTS + row] = fmaxf(best[r] + x2[r], 0.0f);
    }
}

// 64 blocks x 256 threads, 4 rows/thread via float4 loads: min over NCH chunk
// partials per row, sum in double, atomicAdd; last block writes the scalar.
__global__ __launch_bounds__(256) void chamfer_reduce(
    const float* __restrict__ pA, const float* __restrict__ pB,
    double* __restrict__ acc, unsigned int* __restrict__ counter,
    float* __restrict__ out) {
    const int g = blockIdx.x * 256 + threadIdx.x;
    const int r4 = g * 4;
    const int half = NB * NPTS;
    const float* src = (r4 < half) ? pA : pB;
    const int gg = r4 & (half - 1);
    const int b = gg >> 13, r = gg & (NPTS - 1);

    v4f vb = (v4f){3.0e38f, 3.0e38f, 3.0e38f, 3.0e38f};
#pragma unroll 8
    for (int c = 0; c < NCH; ++c) {
        v4f v = *(const v4f*)(src + ((size_t)b * NCH + c) * NPTS + r);
        vb.x = fminf(vb.x, v.x);
        vb.y = fminf(vb.y, v.y);
        vb.z = fminf(vb.z, v.z);
        vb.w = fminf(vb.w, v.w);
    }

    double d = (double)vb.x + (double)vb.y + (double)vb.z + (double)vb.w;
    for (int off = 32; off > 0; off >>= 1) d += __shfl_down(d, off);
    __shared__ double sh[4];
    const int lane = threadIdx.x & 63, wid = threadIdx.x >> 6;
    if (lane == 0) sh[wid] = d;
    __syncthreads();

    if (threadIdx.x == 0) {
        double blocktotal = sh[0] + sh[1] + sh[2] + sh[3];
        atomicAdd(acc, blocktotal);
        __threadfence();
        unsigned int ticket = atomicAdd(counter, 1u);
        if (ticket == gridDim.x - 1) {
            __threadfence();
            double s = atomicAdd(acc, 0.0);
            out[0] = (float)(s / (double)(NB * NPTS));
        }
    }
}

extern "C" void kernel_launch(void* const* d_in, const int* in_sizes, int n_in,
                              void* d_out, int out_size, void* d_ws, size_t ws_size,
                              hipStream_t stream) {
    const float* pred = (const float*)d_in[0];  // [B, N, 3]
    const float* targ = (const float*)d_in[1];  // [B, M, 3]
    float* out = (float*)d_out;

    float* pA = (float*)d_ws;                               // 4 MB
    float* pB = pA + (size_t)NB * NCH * NPTS;               // 4 MB
    float* pk = pB + (size_t)NB * NCH * NPTS;               // 2*NB*NGRP*16 f = 1 MB
    double* acc = (double*)(pk + (size_t)2 * NB * NGRP * 16);
    unsigned int* counter = (unsigned int*)(acc + 1);

    pack_kernel<<<(2 * NB * NGRP) / 256, 256, 0, stream>>>(pred, targ, pk, acc, counter);

    // 1024 blocks = 4 blocks/CU = 4 waves/SIMD, zero LDS.
    dim3 g1(NPTS / (BLOCK * RPT), NCH, 2 * NB);             // (4, 32, 8)
    chamfer_min_smem<<<g1, BLOCK, 0, stream>>>(pred, targ, pk, pA, pB);

    const int nblk = (2 * NB * NPTS / 4) / 256;             // 64
    chamfer_reduce<<<nblk, 256, 0, stream>>>(pA, pB, acc, counter, out);
}